// Round 1
// baseline (1248.757 us; speedup 1.0000x reference)
//
#include <hip/hip_runtime.h>

// MyEncoder: B=8, S=4096, E=128, D=24, fp32.
// out = softmax((xWq+bq)(xWk+bk)^T / sqrt(128)) (xWv+bv) Wo + bo
// Softmax without max-subtraction (scores are tiny; shift-invariant, fp32-safe)
// => K-split partials are purely additive (sum of l and O).

#define B_ 8
#define S_ 4096
#define E_ 128
#define D_ 24
#define N_ (B_ * S_)          // 32768 rows
#define KSPLIT 4
#define KCHUNK (S_ / KSPLIT)  // 1024 keys per split
#define SCALE 0.08838834764831845f  // 1/sqrt(128)

// ---------------- Kernel 1: QKV projection ----------------
// block=256 -> 2 rows/block, 128 threads per row (cols 0..71 active).
// Q is pre-scaled by SCALE (after bias, matching reference exactly).
__global__ __launch_bounds__(256) void proj_kernel(
    const float* __restrict__ x,
    const float* __restrict__ wQ, const float* __restrict__ bQ,
    const float* __restrict__ wK, const float* __restrict__ bK,
    const float* __restrict__ wV, const float* __restrict__ bV,
    float* __restrict__ Qb, float* __restrict__ Kb, float* __restrict__ Vb)
{
    const int tid = threadIdx.x;
    const int c   = tid & 127;                 // 0..127
    const int row = blockIdx.x * 2 + (tid >> 7);
    if (c >= 3 * D_) return;
    const int which = c / D_;                  // 0=Q,1=K,2=V
    const int cc    = c % D_;
    const float* __restrict__ w  = (which == 0) ? wQ : (which == 1) ? wK : wV;
    const float* __restrict__ bb = (which == 0) ? bQ : (which == 1) ? bK : bV;
    float acc = bb[cc];
    const float* __restrict__ xr = x + (size_t)row * E_;
    #pragma unroll 16
    for (int k = 0; k < E_; ++k)
        acc = fmaf(xr[k], w[k * D_ + cc], acc);
    float* __restrict__ o = (which == 0) ? Qb : (which == 1) ? Kb : Vb;
    o[(size_t)row * D_ + cc] = (which == 0) ? acc * SCALE : acc;
}

// ---------------- Kernel 2: attention partials ----------------
// One thread per query; K/V rows are wave-uniform (loop/block indexed) so the
// compiler can scalarize them (s_load) and feed v_fma with an SGPR operand.
// Each block: 256 queries x 1024 keys (split blockIdx.y of 4).
__global__ __launch_bounds__(256) void attn_kernel(
    const float* __restrict__ Qb, const float* __restrict__ Kb,
    const float* __restrict__ Vb,
    float* __restrict__ Op, float* __restrict__ lp)
{
    const int tid   = threadIdx.x;
    const int qblk  = blockIdx.x;     // 0..127
    const int split = blockIdx.y;     // 0..KSPLIT-1
    const int q     = qblk * 256 + tid;      // global query row
    const int b     = q >> 12;               // q / 4096

    float Q[D_];
    const float* __restrict__ qr = Qb + (size_t)q * D_;
    #pragma unroll
    for (int j = 0; j < D_; ++j) Q[j] = qr[j];

    float O[D_];
    #pragma unroll
    for (int d = 0; d < D_; ++d) O[d] = 0.0f;
    float l = 0.0f;

    const int kbase = b * S_ + split * KCHUNK;
    const float* __restrict__ Kp = Kb + (size_t)kbase * D_;
    const float* __restrict__ Vp = Vb + (size_t)kbase * D_;

    for (int k = 0; k < KCHUNK; ++k) {
        const float* __restrict__ kr = Kp + k * D_;  // wave-uniform address
        const float* __restrict__ vr = Vp + k * D_;
        float s = 0.0f;
        #pragma unroll
        for (int j = 0; j < D_; ++j) s = fmaf(Q[j], kr[j], s);
        const float p = __expf(s);
        l += p;
        #pragma unroll
        for (int d = 0; d < D_; ++d) O[d] = fmaf(p, vr[d], O[d]);
    }

    lp[(size_t)split * N_ + q] = l;
    float* __restrict__ op = Op + ((size_t)split * N_ + q) * D_;
    #pragma unroll
    for (int d = 0; d < D_; ++d) op[d] = O[d];
}

// ---------------- Kernel 3: combine + output projection ----------------
// One wave per row: sum KSPLIT partials, H = O/l, out = H*wO + bO.
__global__ __launch_bounds__(256) void out_kernel(
    const float* __restrict__ Op, const float* __restrict__ lp,
    const float* __restrict__ wO, const float* __restrict__ bO,
    float* __restrict__ out)
{
    const int lane = threadIdx.x & 63;
    const int wave = threadIdx.x >> 6;
    const int r    = blockIdx.x * 4 + wave;    // row 0..N_-1

    float l = 0.0f;
    #pragma unroll
    for (int s = 0; s < KSPLIT; ++s) l += lp[(size_t)s * N_ + r];
    const float inv = 1.0f / l;

    float H[D_];
    #pragma unroll
    for (int d = 0; d < D_; ++d) {
        float o = 0.0f;
        #pragma unroll
        for (int s = 0; s < KSPLIT; ++s)
            o += Op[((size_t)s * N_ + r) * D_ + d];
        H[d] = o * inv;
    }

    #pragma unroll
    for (int half = 0; half < 2; ++half) {
        const int e = lane + half * 64;
        float acc = bO[e];
        #pragma unroll
        for (int d = 0; d < D_; ++d)
            acc = fmaf(H[d], wO[d * E_ + e], acc);
        out[(size_t)r * E_ + e] = acc;
    }
}

extern "C" void kernel_launch(void* const* d_in, const int* in_sizes, int n_in,
                              void* d_out, int out_size, void* d_ws, size_t ws_size,
                              hipStream_t stream) {
    const float* x  = (const float*)d_in[0];
    const float* wQ = (const float*)d_in[1];
    const float* bQ = (const float*)d_in[2];
    const float* wK = (const float*)d_in[3];
    const float* bK = (const float*)d_in[4];
    const float* wV = (const float*)d_in[5];
    const float* bV = (const float*)d_in[6];
    const float* wO = (const float*)d_in[7];
    const float* bO = (const float*)d_in[8];
    float* out = (float*)d_out;

    float* ws = (float*)d_ws;
    float* Qb = ws;
    float* Kb = ws + (size_t)N_ * D_;
    float* Vb = ws + 2 * (size_t)N_ * D_;
    float* Op = ws + 3 * (size_t)N_ * D_;                 // KSPLIT * N_ * D_
    float* lp = ws + (3 + KSPLIT) * (size_t)N_ * D_;      // KSPLIT * N_

    proj_kernel<<<N_ / 2, 256, 0, stream>>>(x, wQ, bQ, wK, bK, wV, bV, Qb, Kb, Vb);
    attn_kernel<<<dim3(N_ / 256, KSPLIT), 256, 0, stream>>>(Qb, Kb, Vb, Op, lp);
    out_kernel<<<N_ / 4, 256, 0, stream>>>(Op, lp, wO, bO, out);
}

// Round 2
// 404.599 us; speedup vs baseline: 3.0864x; 3.0864x over previous
//
#include <hip/hip_runtime.h>

// MyEncoder: B=8, S=4096, E=128, D=24, fp32.
// out = softmax((xWq+bq)(xWk+bk)^T / sqrt(128)) (xWv+bv) Wo + bo
// Softmax without max-subtraction (scores tiny, shift-invariant) => K-split
// partials are purely additive.

#define B_ 8
#define S_ 4096
#define E_ 128
#define D_ 24
#define N_ (B_ * S_)          // 32768 rows
#define TK 64                 // keys per LDS tile
#define SCALE 0.08838834764831845f  // 1/sqrt(128)

// ---------------- Kernel 1: QKV projection ----------------
// block=256 -> 2 rows/block, 128 threads per row (cols 0..71 active).
// Q pre-scaled by SCALE. float4 x loads, fully unrolled.
__global__ __launch_bounds__(256) void proj_kernel(
    const float* __restrict__ x,
    const float* __restrict__ wQ, const float* __restrict__ bQ,
    const float* __restrict__ wK, const float* __restrict__ bK,
    const float* __restrict__ wV, const float* __restrict__ bV,
    float* __restrict__ Qb, float* __restrict__ Kb, float* __restrict__ Vb)
{
    const int tid = threadIdx.x;
    const int c   = tid & 127;
    const int row = blockIdx.x * 2 + (tid >> 7);
    if (c >= 3 * D_) return;
    const int which = c / D_;
    const int cc    = c % D_;
    const float* __restrict__ w  = (which == 0) ? wQ : (which == 1) ? wK : wV;
    const float* __restrict__ bb = (which == 0) ? bQ : (which == 1) ? bK : bV;
    float acc = bb[cc];
    const float4* __restrict__ xr4 = (const float4*)(x + (size_t)row * E_);
    #pragma unroll
    for (int k4 = 0; k4 < E_ / 4; ++k4) {
        const float4 xv = xr4[k4];
        const int kb = k4 * 4;
        acc = fmaf(xv.x, w[(kb + 0) * D_ + cc], acc);
        acc = fmaf(xv.y, w[(kb + 1) * D_ + cc], acc);
        acc = fmaf(xv.z, w[(kb + 2) * D_ + cc], acc);
        acc = fmaf(xv.w, w[(kb + 3) * D_ + cc], acc);
    }
    float* __restrict__ o = (which == 0) ? Qb : (which == 1) ? Kb : Vb;
    o[(size_t)row * D_ + cc] = (which == 0) ? acc * SCALE : acc;
}

// ---------------- Kernel 2: attention partials ----------------
// Block = 256 threads, 2 queries/thread -> 512 queries/block.
// K/V tiles staged in LDS; inner loop reads rows via broadcast ds_read_b128.
// grid = (N/512, ksplit); each block streams S/ksplit keys.
__global__ __launch_bounds__(256, 2) void attn_kernel(
    const float* __restrict__ Qb, const float* __restrict__ Kb,
    const float* __restrict__ Vb,
    float* __restrict__ Op, float* __restrict__ lp)
{
    __shared__ float Ks[TK * D_];
    __shared__ float Vs[TK * D_];

    const int tid    = threadIdx.x;
    const int qblk   = blockIdx.x;
    const int split  = blockIdx.y;
    const int nsplit = gridDim.y;
    const int kchunk = S_ / nsplit;

    const int q0 = qblk * 512 + tid;       // thread's two query rows
    const int q1 = q0 + 256;
    const int b  = q0 >> 12;               // batch (512 | 4096, same for q1)

    float Q0[D_], Q1[D_];
    {
        const float* __restrict__ qr0 = Qb + (size_t)q0 * D_;
        const float* __restrict__ qr1 = Qb + (size_t)q1 * D_;
        #pragma unroll
        for (int j = 0; j < D_; ++j) { Q0[j] = qr0[j]; Q1[j] = qr1[j]; }
    }

    float O0[D_], O1[D_];
    #pragma unroll
    for (int d = 0; d < D_; ++d) { O0[d] = 0.0f; O1[d] = 0.0f; }
    float l0 = 0.0f, l1 = 0.0f;

    const int kstart = b * S_ + split * kchunk;

    for (int kt = 0; kt < kchunk; kt += TK) {
        // ---- stage TK keys of K and V into LDS (float4 coalesced) ----
        const float4* __restrict__ ksrc = (const float4*)(Kb + (size_t)(kstart + kt) * D_);
        const float4* __restrict__ vsrc = (const float4*)(Vb + (size_t)(kstart + kt) * D_);
        float4* __restrict__ kdst = (float4*)Ks;
        float4* __restrict__ vdst = (float4*)Vs;
        #pragma unroll
        for (int i = tid; i < TK * D_ / 4; i += 256) {
            kdst[i] = ksrc[i];
            vdst[i] = vsrc[i];
        }
        __syncthreads();

        #pragma unroll 2
        for (int k = 0; k < TK; ++k) {
            const float* __restrict__ kr = &Ks[k * D_];
            float s0a = 0.0f, s0b = 0.0f, s1a = 0.0f, s1b = 0.0f;
            #pragma unroll
            for (int j = 0; j < 12; ++j) {
                s0a = fmaf(Q0[j], kr[j], s0a);
                s1a = fmaf(Q1[j], kr[j], s1a);
            }
            #pragma unroll
            for (int j = 12; j < D_; ++j) {
                s0b = fmaf(Q0[j], kr[j], s0b);
                s1b = fmaf(Q1[j], kr[j], s1b);
            }
            const float p0 = __expf(s0a + s0b);
            const float p1 = __expf(s1a + s1b);
            l0 += p0; l1 += p1;
            const float* __restrict__ vr = &Vs[k * D_];
            #pragma unroll
            for (int d = 0; d < D_; ++d) {
                O0[d] = fmaf(p0, vr[d], O0[d]);
                O1[d] = fmaf(p1, vr[d], O1[d]);
            }
        }
        __syncthreads();
    }

    lp[(size_t)split * N_ + q0] = l0;
    lp[(size_t)split * N_ + q1] = l1;
    float* __restrict__ op0 = Op + ((size_t)split * N_ + q0) * D_;
    float* __restrict__ op1 = Op + ((size_t)split * N_ + q1) * D_;
    #pragma unroll
    for (int d = 0; d < D_; ++d) { op0[d] = O0[d]; op1[d] = O1[d]; }
}

// ---------------- Kernel 3: combine + output projection ----------------
// One wave per row. Lanes 0..23 gather partial O sums (coalesced across d),
// then __shfl broadcasts H[d] for the wO product. 2 output cols per lane.
__global__ __launch_bounds__(256) void out_kernel(
    const float* __restrict__ Op, const float* __restrict__ lp,
    const float* __restrict__ wO, const float* __restrict__ bO,
    float* __restrict__ out, int ksplit)
{
    const int lane = threadIdx.x & 63;
    const int wave = threadIdx.x >> 6;
    const int r    = blockIdx.x * 4 + wave;

    float l = 0.0f;
    for (int s = 0; s < ksplit; ++s) l += lp[(size_t)s * N_ + r];

    float Hd = 0.0f;
    if (lane < D_) {
        for (int s = 0; s < ksplit; ++s)
            Hd += Op[((size_t)s * N_ + r) * D_ + lane];
        Hd *= (1.0f / l);
    }

    float acc0 = bO[lane];
    float acc1 = bO[lane + 64];
    #pragma unroll
    for (int d = 0; d < D_; ++d) {
        const float h = __shfl(Hd, d, 64);
        acc0 = fmaf(h, wO[d * E_ + lane],      acc0);
        acc1 = fmaf(h, wO[d * E_ + 64 + lane], acc1);
    }
    out[(size_t)r * E_ + lane]      = acc0;
    out[(size_t)r * E_ + 64 + lane] = acc1;
}

extern "C" void kernel_launch(void* const* d_in, const int* in_sizes, int n_in,
                              void* d_out, int out_size, void* d_ws, size_t ws_size,
                              hipStream_t stream) {
    const float* x  = (const float*)d_in[0];
    const float* wQ = (const float*)d_in[1];
    const float* bQ = (const float*)d_in[2];
    const float* wK = (const float*)d_in[3];
    const float* bK = (const float*)d_in[4];
    const float* wV = (const float*)d_in[5];
    const float* bV = (const float*)d_in[6];
    const float* wO = (const float*)d_in[7];
    const float* bO = (const float*)d_in[8];
    float* out = (float*)d_out;

    // choose ksplit by workspace capacity: need (3+ks)*N*D + ks*N floats
    int ksplit = 8;
    {
        size_t need8 = ((size_t)(3 + 8) * N_ * D_ + (size_t)8 * N_) * sizeof(float);
        if (ws_size < need8) ksplit = 4;
    }

    float* ws = (float*)d_ws;
    float* Qb = ws;
    float* Kb = ws + (size_t)N_ * D_;
    float* Vb = ws + 2 * (size_t)N_ * D_;
    float* Op = ws + 3 * (size_t)N_ * D_;                      // ksplit*N*D
    float* lp = ws + (size_t)(3 + ksplit) * N_ * D_;           // ksplit*N

    proj_kernel<<<N_ / 2, 256, 0, stream>>>(x, wQ, bQ, wK, bK, wV, bV, Qb, Kb, Vb);
    attn_kernel<<<dim3(N_ / 512, ksplit), 256, 0, stream>>>(Qb, Kb, Vb, Op, lp);
    out_kernel<<<N_ / 4, 256, 0, stream>>>(Op, lp, wO, bO, out, ksplit);
}

// Round 4
// 172.232 us; speedup vs baseline: 7.2504x; 2.3492x over previous
//
#include <hip/hip_runtime.h>

// MyEncoder: B=8, S=4096, E=128, D=24, fp32 in/out.
// out = softmax((xWq+bq)(xWk+bk)^T / sqrt(128)) (xWv+bv) Wo + bo
// Full bf16-MFMA pipeline: prep (pack weights) -> proj (QKV GEMM) -> attn
// (flash, fused output projection). Softmax without max-subtraction (scores
// tiny, shift-invariant) => plain additive l, no online rescale.

#define B_ 8
#define S_ 4096
#define E_ 128
#define D_ 24
#define N_ (B_ * S_)               // 32768 rows
#define SCALE 0.08838834764831845f // 1/sqrt(128)

#define TK 128                     // keys per LDS tile in attn
#define KS_STRIDE 40               // K_s row stride (bf16)
#define VS_STRIDE 136              // V_s row stride (bf16)
#define PS_STRIDE 40               // P_s row stride (bf16)
#define XS_STRIDE 136              // x_s row stride (bf16) in proj
#define OS_STRIDE 84               // out_s row stride (fp32) in proj

typedef __attribute__((ext_vector_type(8))) short bfrag;   // 8 bf16 = 4 VGPR
typedef __attribute__((ext_vector_type(4))) float ffrag;   // 4 fp32 acc

__device__ inline unsigned short f2bf(float f) {           // RNE fp32->bf16
    unsigned int x = __builtin_bit_cast(unsigned int, f);
    return (unsigned short)((x + 0x7fffu + ((x >> 16) & 1u)) >> 16);
}
__device__ inline unsigned int pack2(float a, float b) {
    return (unsigned int)f2bf(a) | ((unsigned int)f2bf(b) << 16);
}

// ---------------- Kernel 0: weight prep (1 block) ----------------
// Wf  [kt=4][nt=5][lane=64][j=8]: W[k][n], k=kt*32+quad*8+j, n=nt*16+(lane&15)
//     W = [wQ*SCALE | wK | wV | 0pad] (128 x 80)
// wOf [nt=8][lane=64][j=8]: wO[k][e] with k=quad*8+j (zero for k>=24)
// bqkv[80] fp32 = [bQ*SCALE | bK | bV | 0]
__global__ __launch_bounds__(256) void prep_kernel(
    const float* __restrict__ wQ, const float* __restrict__ bQ,
    const float* __restrict__ wK, const float* __restrict__ bK,
    const float* __restrict__ wV, const float* __restrict__ bV,
    const float* __restrict__ wO,
    unsigned short* __restrict__ Wf, unsigned short* __restrict__ wOf,
    float* __restrict__ bqkv)
{
    const int tid = threadIdx.x;
    for (int idx = tid; idx < 4 * 5 * 512; idx += 256) {
        const int j    = idx & 7;
        const int lane = (idx >> 3) & 63;
        const int nt   = (idx >> 9) % 5;
        const int kt   = idx / 2560;
        const int n = nt * 16 + (lane & 15);
        const int k = kt * 32 + ((lane >> 4) << 3) + j;
        float v = 0.0f;
        if (n < 24)      v = wQ[k * 24 + n] * SCALE;
        else if (n < 48) v = wK[k * 24 + (n - 24)];
        else if (n < 72) v = wV[k * 24 + (n - 48)];
        Wf[idx] = f2bf(v);
    }
    for (int idx = tid; idx < 8 * 512; idx += 256) {
        const int j    = idx & 7;
        const int lane = (idx >> 3) & 63;
        const int nt   = idx >> 9;
        const int k = ((lane >> 4) << 3) + j;
        const int e = nt * 16 + (lane & 15);
        wOf[idx] = (k < 24) ? f2bf(wO[k * 128 + e]) : (unsigned short)0;
    }
    if (tid < 80) {
        float v = 0.0f;
        if (tid < 24)      v = bQ[tid] * SCALE;
        else if (tid < 48) v = bK[tid - 24];
        else if (tid < 72) v = bV[tid - 48];
        bqkv[tid] = v;
    }
}

// ---------------- Kernel 1: QKV projection (MFMA) ----------------
// 64 rows/block, 4 waves x 16 rows. x (fp32) -> bf16 LDS; W frags from Wf.
// Epilogue: bias add -> LDS fp32 tile -> write Qbf/Kbf (row-major, 32-padded)
// and Vt (transposed, [b][d][s]).
__global__ __launch_bounds__(256) void proj_kernel(
    const float* __restrict__ x, const unsigned short* __restrict__ Wf,
    const float* __restrict__ bqkv,
    unsigned short* __restrict__ Qbf, unsigned short* __restrict__ Kbf,
    unsigned short* __restrict__ Vt)
{
    __shared__ float smem[64 * OS_STRIDE];          // 21504 B, dual-purpose
    unsigned short* xs = (unsigned short*)smem;     // [64][XS_STRIDE]
    float* os = smem;                               // [64][OS_STRIDE]

    const int tid  = threadIdx.x;
    const int lane = tid & 63;
    const int w    = tid >> 6;
    const int col  = lane & 15;
    const int quad = lane >> 4;
    const int rb   = blockIdx.x * 64;

    // stage x -> bf16 LDS
    #pragma unroll
    for (int i = 0; i < 8; ++i) {
        const int idx = i * 256 + tid;              // 0..2047
        const int row = idx >> 5, c4 = idx & 31;
        const float4 xv = *(const float4*)(x + (size_t)(rb + row) * 128 + c4 * 4);
        uint2 h;
        h.x = pack2(xv.x, xv.y);
        h.y = pack2(xv.z, xv.w);
        *(uint2*)(&xs[row * XS_STRIDE + c4 * 4]) = h;
    }

    // load W fragments (20 x 16B, coalesced)
    bfrag Wfr[20];
    #pragma unroll
    for (int f = 0; f < 20; ++f)
        Wfr[f] = *(const bfrag*)(Wf + (f * 64 + lane) * 8);

    __syncthreads();

    ffrag acc[5];
    #pragma unroll
    for (int nt = 0; nt < 5; ++nt) acc[nt] = (ffrag){0.f, 0.f, 0.f, 0.f};

    #pragma unroll
    for (int kt = 0; kt < 4; ++kt) {
        const bfrag Af = *(const bfrag*)(&xs[(w * 16 + col) * XS_STRIDE + kt * 32 + quad * 8]);
        #pragma unroll
        for (int nt = 0; nt < 5; ++nt)
            acc[nt] = __builtin_amdgcn_mfma_f32_16x16x32_bf16(Af, Wfr[kt * 5 + nt], acc[nt], 0, 0, 0);
    }

    __syncthreads();  // reuse smem as fp32 out tile

    #pragma unroll
    for (int nt = 0; nt < 5; ++nt) {
        const float bb = bqkv[nt * 16 + col];
        #pragma unroll
        for (int r = 0; r < 4; ++r)
            os[(w * 16 + quad * 4 + r) * OS_STRIDE + nt * 16 + col] = acc[nt][r] + bb;
    }
    __syncthreads();

    // write Q (tid<128) / K (tid>=128): row-major bf16, cols padded to 32.
    // Clean 16-col pack (round-2 had cols 10,11 mis-packed with 12,13's values).
    {
        const int half  = tid & 1;
        const int row   = (tid >> 1) & 63;
        const int isK   = tid >> 7;
        const int cbase = isK * 24;
        unsigned int pk[8];
        #pragma unroll
        for (int g = 0; g < 8; ++g) {
            const int c0 = half * 16 + g * 2;
            const float f0 = (c0     < 24) ? os[row * OS_STRIDE + cbase + c0]     : 0.0f;
            const float f1 = (c0 + 1 < 24) ? os[row * OS_STRIDE + cbase + c0 + 1] : 0.0f;
            pk[g] = pack2(f0, f1);
        }
        unsigned short* dst = (isK ? Kbf : Qbf) + (size_t)(rb + row) * 32 + half * 16;
        *(uint4*)(dst)     = make_uint4(pk[0], pk[1], pk[2], pk[3]);
        *(uint4*)(dst + 8) = make_uint4(pk[4], pk[5], pk[6], pk[7]);
    }

    // write Vt: d-fast assignment (LDS conflict-free), 16B stores
    if (tid < 192) {
        const int d  = tid % 24;
        const int ch = tid / 24;                     // 0..7
        unsigned int p[4];
        #pragma unroll
        for (int g = 0; g < 4; ++g) {
            const float f0 = os[(ch * 8 + g * 2 + 0) * OS_STRIDE + 48 + d];
            const float f1 = os[(ch * 8 + g * 2 + 1) * OS_STRIDE + 48 + d];
            p[g] = pack2(f0, f1);
        }
        const int b = rb >> 12, s0 = rb & 4095;
        uint4* dst = (uint4*)(Vt + (((size_t)(b * 24 + d)) << 12) + s0 + ch * 8);
        *dst = make_uint4(p[0], p[1], p[2], p[3]);
    }
}

// ---------------- Kernel 2: flash attention + fused output proj ----------------
// 64 queries/block (4 waves x 16). Streams all 4096 keys in TK=128 LDS tiles.
__global__ __launch_bounds__(256) void attn_kernel(
    const unsigned short* __restrict__ Qbf, const unsigned short* __restrict__ Kbf,
    const unsigned short* __restrict__ Vt,  const unsigned short* __restrict__ wOf,
    const float* __restrict__ bO, float* __restrict__ out)
{
    __shared__ unsigned short Ks[TK * KS_STRIDE];    // 10240 B
    __shared__ unsigned short Vs[32 * VS_STRIDE];    // 8704 B (rows 24-31 junk, masked in epilogue)
    __shared__ unsigned short Ps[4 * 16 * PS_STRIDE];// 5120 B (per-wave private)

    const int tid   = threadIdx.x;
    const int lane  = tid & 63;
    const int w     = tid >> 6;
    const int col   = lane & 15;
    const int quad  = lane >> 4;
    const int blk   = blockIdx.x;
    const int b     = blk >> 6;
    const int qbase = blk * 64 + w * 16;

    // Q A-fragment (16 queries x 32 padded d)
    const bfrag Qf = *(const bfrag*)(Qbf + (size_t)(qbase + col) * 32 + quad * 8);
    // wO B-fragments
    bfrag Wo[8];
    #pragma unroll
    for (int nt = 0; nt < 8; ++nt)
        Wo[nt] = *(const bfrag*)(wOf + (nt * 64 + lane) * 8);

    ffrag O0 = {0.f, 0.f, 0.f, 0.f};
    ffrag O1 = {0.f, 0.f, 0.f, 0.f};
    float lacc[4] = {0.f, 0.f, 0.f, 0.f};

    const unsigned short* Kbase = Kbf + (size_t)(b * 4096) * 32;
    const unsigned short* Vbase = Vt + (size_t)(b * 24) * 4096;
    unsigned short* Pw = &Ps[w * 16 * PS_STRIDE];

    for (int kb = 0; kb < S_; kb += TK) {
        // ---- stage K tile: 128 rows x 32 bf16 ----
        #pragma unroll
        for (int i = 0; i < 2; ++i) {
            const int idx = i * 256 + tid;           // 0..511
            const int key = idx >> 2, ch = idx & 3;
            const uint4 t4 = *(const uint4*)(Kbase + (size_t)(kb + key) * 32 + ch * 8);
            *(uint4*)(&Ks[key * KS_STRIDE + ch * 8]) = t4;
        }
        // ---- stage V tile: 24 d-rows x 128 keys ----
        #pragma unroll
        for (int i = 0; i < 2; ++i) {
            const int idx = i * 256 + tid;
            if (idx < 384) {
                const int d = idx >> 4, ch = idx & 15;
                const uint4 t4 = *(const uint4*)(Vbase + (size_t)d * 4096 + kb + ch * 8);
                *(uint4*)(&Vs[d * VS_STRIDE + ch * 8]) = t4;
            }
        }
        __syncthreads();

        #pragma unroll
        for (int kb2 = 0; kb2 < TK; kb2 += 32) {
            // QK^T: two 16-key fragments
            const bfrag Kf0 = *(const bfrag*)(&Ks[(kb2 + col) * KS_STRIDE + quad * 8]);
            const bfrag Kf1 = *(const bfrag*)(&Ks[(kb2 + 16 + col) * KS_STRIDE + quad * 8]);
            ffrag S0 = {0.f, 0.f, 0.f, 0.f};
            ffrag S1 = {0.f, 0.f, 0.f, 0.f};
            S0 = __builtin_amdgcn_mfma_f32_16x16x32_bf16(Qf, Kf0, S0, 0, 0, 0);
            S1 = __builtin_amdgcn_mfma_f32_16x16x32_bf16(Qf, Kf1, S1, 0, 0, 0);
            // exp (no max subtraction), accumulate l, write P (bf16) to LDS
            #pragma unroll
            for (int r = 0; r < 4; ++r) {
                const float p0 = __expf(S0[r]);
                const float p1 = __expf(S1[r]);
                lacc[r] += p0 + p1;
                Pw[(quad * 4 + r) * PS_STRIDE + col]      = f2bf(p0);
                Pw[(quad * 4 + r) * PS_STRIDE + 16 + col] = f2bf(p1);
            }
            // P as A-fragment (wave-private LDS round trip, no barrier)
            const bfrag Pf  = *(const bfrag*)(&Pw[col * PS_STRIDE + quad * 8]);
            const bfrag Vf0 = *(const bfrag*)(&Vs[col * VS_STRIDE + kb2 + quad * 8]);
            const bfrag Vf1 = *(const bfrag*)(&Vs[(16 + col) * VS_STRIDE + kb2 + quad * 8]);
            O0 = __builtin_amdgcn_mfma_f32_16x16x32_bf16(Pf, Vf0, O0, 0, 0, 0);
            O1 = __builtin_amdgcn_mfma_f32_16x16x32_bf16(Pf, Vf1, O1, 0, 0, 0);
        }
        __syncthreads();
    }

    // ---- epilogue: reduce l over the 16 key-lanes, H = O/l ----
    float invl[4];
    #pragma unroll
    for (int r = 0; r < 4; ++r) {
        float v = lacc[r];
        v += __shfl_xor(v, 1);
        v += __shfl_xor(v, 2);
        v += __shfl_xor(v, 4);
        v += __shfl_xor(v, 8);
        invl[r] = 1.0f / v;
    }
    // H -> LDS (reuse Ps), padded d 24..31 = 0
    #pragma unroll
    for (int r = 0; r < 4; ++r) {
        const float h0 = O0[r] * invl[r];
        const float h1 = (col < 8) ? O1[r] * invl[r] : 0.0f;
        Pw[(quad * 4 + r) * PS_STRIDE + col]      = f2bf(h0);
        Pw[(quad * 4 + r) * PS_STRIDE + 16 + col] = f2bf(h1);
    }
    const bfrag Hf = *(const bfrag*)(&Pw[col * PS_STRIDE + quad * 8]);
    #pragma unroll
    for (int nt = 0; nt < 8; ++nt) {
        ffrag C = {0.f, 0.f, 0.f, 0.f};
        C = __builtin_amdgcn_mfma_f32_16x16x32_bf16(Hf, Wo[nt], C, 0, 0, 0);
        const float bo = bO[nt * 16 + col];
        #pragma unroll
        for (int r = 0; r < 4; ++r)
            out[(size_t)(qbase + quad * 4 + r) * 128 + nt * 16 + col] = C[r] + bo;
    }
}

extern "C" void kernel_launch(void* const* d_in, const int* in_sizes, int n_in,
                              void* d_out, int out_size, void* d_ws, size_t ws_size,
                              hipStream_t stream) {
    const float* x  = (const float*)d_in[0];
    const float* wQ = (const float*)d_in[1];
    const float* bQ = (const float*)d_in[2];
    const float* wK = (const float*)d_in[3];
    const float* bK = (const float*)d_in[4];
    const float* wV = (const float*)d_in[5];
    const float* bV = (const float*)d_in[6];
    const float* wO = (const float*)d_in[7];
    const float* bO = (const float*)d_in[8];
    float* out = (float*)d_out;

    unsigned short* ws16 = (unsigned short*)d_ws;
    unsigned short* Qbf = ws16;                                    // N*32
    unsigned short* Kbf = Qbf + (size_t)N_ * 32;                   // N*32
    unsigned short* Vt  = Kbf + (size_t)N_ * 32;                   // B*24*S
    unsigned short* Wf  = Vt + (size_t)B_ * 24 * S_;               // 10240
    unsigned short* wOf = Wf + 4 * 5 * 512;                        // 4096
    float* bqkv = (float*)(wOf + 8 * 512);                         // 80 fp32

    prep_kernel<<<1, 256, 0, stream>>>(wQ, bQ, wK, bK, wV, bV, wO, Wf, wOf, bqkv);
    proj_kernel<<<N_ / 64, 256, 0, stream>>>(x, Wf, bqkv, Qbf, Kbf, Vt);
    attn_kernel<<<N_ / 64, 256, 0, stream>>>(Qbf, Kbf, Vt, wOf, bO, out);
}

// Round 5
// 165.599 us; speedup vs baseline: 7.5409x; 1.0401x over previous
//
#include <hip/hip_runtime.h>

// MyEncoder: B=8, S=4096, E=128, D=24, fp32 in/out.
// out = softmax((xWq+bq)(xWk+bk)^T / sqrt(128)) (xWv+bv) Wo + bo
// bf16-MFMA pipeline: prep -> proj (QKV GEMM) -> attn (flash partials,
// K-split) -> combine (sum partials + wO epilogue).
// Softmax without max-subtraction (scores tiny, shift-invariant) => K-split
// partials are purely additive (sum O, sum l). exp via exp2 with log2(e)
// folded into the Q scale.

#define B_ 8
#define S_ 4096
#define E_ 128
#define D_ 24
#define N_ (B_ * S_)               // 32768 rows
#define SCALE 0.08838834764831845f // 1/sqrt(128)
#define LOG2E 1.4426950408889634f

#define TK 64                      // keys per LDS tile in attn
#define KS_STRIDE 40               // K_s row stride (bf16 shorts)
#define VS_STRIDE 72               // V_s row stride (bf16 shorts)
#define PS_STRIDE 40               // P_s row stride (bf16 shorts)
#define HS_STRIDE 40               // H_s row stride in combine
#define XS_STRIDE 136              // x_s row stride (bf16) in proj
#define OS_STRIDE 84               // out_s row stride (fp32) in proj

typedef __attribute__((ext_vector_type(8))) short bfrag;   // 8 bf16 = 4 VGPR
typedef __attribute__((ext_vector_type(4))) float ffrag;   // 4 fp32 acc

__device__ inline unsigned short f2bf(float f) {           // RNE fp32->bf16
    unsigned int x = __builtin_bit_cast(unsigned int, f);
    return (unsigned short)((x + 0x7fffu + ((x >> 16) & 1u)) >> 16);
}
__device__ inline unsigned int pack2(float a, float b) {
    return (unsigned int)f2bf(a) | ((unsigned int)f2bf(b) << 16);
}

// ---------------- Kernel 0: weight prep (1 block) ----------------
// Wf  [kt=4][nt=5][lane=64][j=8]: W[k][n], k=kt*32+quad*8+j, n=nt*16+(lane&15)
//     W = [wQ*SCALE*LOG2E | wK | wV | 0pad] (128 x 80)
// wOf [nt=8][lane=64][j=8]: wO[k][e], k=quad*8+j (zero for k>=24)
// bqkv[80] fp32 = [bQ*SCALE*LOG2E | bK | bV | 0]
__global__ __launch_bounds__(256) void prep_kernel(
    const float* __restrict__ wQ, const float* __restrict__ bQ,
    const float* __restrict__ wK, const float* __restrict__ bK,
    const float* __restrict__ wV, const float* __restrict__ bV,
    const float* __restrict__ wO,
    unsigned short* __restrict__ Wf, unsigned short* __restrict__ wOf,
    float* __restrict__ bqkv)
{
    const int tid = threadIdx.x;
    const float qs = SCALE * LOG2E;
    for (int idx = tid; idx < 4 * 5 * 512; idx += 256) {
        const int j    = idx & 7;
        const int lane = (idx >> 3) & 63;
        const int nt   = (idx >> 9) % 5;
        const int kt   = idx / 2560;
        const int n = nt * 16 + (lane & 15);
        const int k = kt * 32 + ((lane >> 4) << 3) + j;
        float v = 0.0f;
        if (n < 24)      v = wQ[k * 24 + n] * qs;
        else if (n < 48) v = wK[k * 24 + (n - 24)];
        else if (n < 72) v = wV[k * 24 + (n - 48)];
        Wf[idx] = f2bf(v);
    }
    for (int idx = tid; idx < 8 * 512; idx += 256) {
        const int j    = idx & 7;
        const int lane = (idx >> 3) & 63;
        const int nt   = idx >> 9;
        const int k = ((lane >> 4) << 3) + j;
        const int e = nt * 16 + (lane & 15);
        wOf[idx] = (k < 24) ? f2bf(wO[k * 128 + e]) : (unsigned short)0;
    }
    if (tid < 80) {
        float v = 0.0f;
        if (tid < 24)      v = bQ[tid] * qs;
        else if (tid < 48) v = bK[tid - 24];
        else if (tid < 72) v = bV[tid - 48];
        bqkv[tid] = v;
    }
}

// ---------------- Kernel 1: QKV projection (MFMA) ----------------
// 64 rows/block, 4 waves x 16 rows. x (fp32) -> bf16 LDS; W frags from Wf.
// Epilogue: bias add -> LDS fp32 tile -> Qbf/Kbf (row-major, 32-padded) and
// Vt (transposed, [b][d][s]).
__global__ __launch_bounds__(256) void proj_kernel(
    const float* __restrict__ x, const unsigned short* __restrict__ Wf,
    const float* __restrict__ bqkv,
    unsigned short* __restrict__ Qbf, unsigned short* __restrict__ Kbf,
    unsigned short* __restrict__ Vt)
{
    __shared__ float smem[64 * OS_STRIDE];          // 21504 B, dual-purpose
    unsigned short* xs = (unsigned short*)smem;     // [64][XS_STRIDE]
    float* os = smem;                               // [64][OS_STRIDE]

    const int tid  = threadIdx.x;
    const int lane = tid & 63;
    const int w    = tid >> 6;
    const int col  = lane & 15;
    const int quad = lane >> 4;
    const int rb   = blockIdx.x * 64;

    #pragma unroll
    for (int i = 0; i < 8; ++i) {
        const int idx = i * 256 + tid;
        const int row = idx >> 5, c4 = idx & 31;
        const float4 xv = *(const float4*)(x + (size_t)(rb + row) * 128 + c4 * 4);
        uint2 h;
        h.x = pack2(xv.x, xv.y);
        h.y = pack2(xv.z, xv.w);
        *(uint2*)(&xs[row * XS_STRIDE + c4 * 4]) = h;
    }

    bfrag Wfr[20];
    #pragma unroll
    for (int f = 0; f < 20; ++f)
        Wfr[f] = *(const bfrag*)(Wf + (f * 64 + lane) * 8);

    __syncthreads();

    ffrag acc[5];
    #pragma unroll
    for (int nt = 0; nt < 5; ++nt) acc[nt] = (ffrag){0.f, 0.f, 0.f, 0.f};

    #pragma unroll
    for (int kt = 0; kt < 4; ++kt) {
        const bfrag Af = *(const bfrag*)(&xs[(w * 16 + col) * XS_STRIDE + kt * 32 + quad * 8]);
        #pragma unroll
        for (int nt = 0; nt < 5; ++nt)
            acc[nt] = __builtin_amdgcn_mfma_f32_16x16x32_bf16(Af, Wfr[kt * 5 + nt], acc[nt], 0, 0, 0);
    }

    __syncthreads();

    #pragma unroll
    for (int nt = 0; nt < 5; ++nt) {
        const float bb = bqkv[nt * 16 + col];
        #pragma unroll
        for (int r = 0; r < 4; ++r)
            os[(w * 16 + quad * 4 + r) * OS_STRIDE + nt * 16 + col] = acc[nt][r] + bb;
    }
    __syncthreads();

    // Q (tid<128) / K (tid>=128): row-major bf16, cols padded to 32
    {
        const int half  = tid & 1;
        const int row   = (tid >> 1) & 63;
        const int isK   = tid >> 7;
        const int cbase = isK * 24;
        unsigned int pk[8];
        #pragma unroll
        for (int g = 0; g < 8; ++g) {
            const int c0 = half * 16 + g * 2;
            const float f0 = (c0     < 24) ? os[row * OS_STRIDE + cbase + c0]     : 0.0f;
            const float f1 = (c0 + 1 < 24) ? os[row * OS_STRIDE + cbase + c0 + 1] : 0.0f;
            pk[g] = pack2(f0, f1);
        }
        unsigned short* dst = (isK ? Kbf : Qbf) + (size_t)(rb + row) * 32 + half * 16;
        *(uint4*)(dst)     = make_uint4(pk[0], pk[1], pk[2], pk[3]);
        *(uint4*)(dst + 8) = make_uint4(pk[4], pk[5], pk[6], pk[7]);
    }

    // Vt: transposed [b][d][s], 16B stores
    if (tid < 192) {
        const int d  = tid % 24;
        const int ch = tid / 24;
        unsigned int p[4];
        #pragma unroll
        for (int g = 0; g < 4; ++g) {
            const float f0 = os[(ch * 8 + g * 2 + 0) * OS_STRIDE + 48 + d];
            const float f1 = os[(ch * 8 + g * 2 + 1) * OS_STRIDE + 48 + d];
            p[g] = pack2(f0, f1);
        }
        const int b = rb >> 12, s0 = rb & 4095;
        uint4* dst = (uint4*)(Vt + (((size_t)(b * 24 + d)) << 12) + s0 + ch * 8);
        *dst = make_uint4(p[0], p[1], p[2], p[3]);
    }
}

// ---------------- Kernel 2: flash attention partials ----------------
// Grid (N/64, KSP). 64 queries/block (4 waves x 16); each block streams
// S/KSP keys in TK=64 tiles. K rows staged even/odd-permuted so the two
// score fragments cover key pairs (2c, 2c+1) -> P pack is one b32 write.
// Writes additive partials: Opart fp32 [split][q][32], lpart [split][q].
__global__ __launch_bounds__(256, 8) void attn_kernel(
    const unsigned short* __restrict__ Qbf, const unsigned short* __restrict__ Kbf,
    const unsigned short* __restrict__ Vt,
    float* __restrict__ Opart, float* __restrict__ lpart)
{
    __shared__ unsigned short Ks[TK * KS_STRIDE];     // 5120 B
    __shared__ unsigned short Vs[32 * VS_STRIDE];     // 4608 B (rows 24-31 junk, masked in combine)
    __shared__ unsigned short Ps[4 * 16 * PS_STRIDE]; // 5120 B (per-wave private)

    const int tid    = threadIdx.x;
    const int lane   = tid & 63;
    const int w      = tid >> 6;
    const int col    = lane & 15;
    const int quad   = lane >> 4;
    const int blk    = blockIdx.x;
    const int split  = blockIdx.y;
    const int nsp    = gridDim.y;
    const int kchunk = S_ / nsp;
    const int b      = blk >> 6;
    const int qbase  = blk * 64 + w * 16;

    const bfrag Qf = *(const bfrag*)(Qbf + (size_t)(qbase + col) * 32 + quad * 8);

    ffrag O0 = {0.f, 0.f, 0.f, 0.f};
    ffrag O1 = {0.f, 0.f, 0.f, 0.f};
    float lacc[4] = {0.f, 0.f, 0.f, 0.f};

    const unsigned short* Kbase = Kbf + ((size_t)(b * 4096) + split * kchunk) * 32;
    const unsigned short* Vbase = Vt + (size_t)(b * 24) * 4096 + split * kchunk;
    unsigned short* Pw = &Ps[w * 16 * PS_STRIDE];

    for (int kb = 0; kb < kchunk; kb += TK) {
        // K tile, even/odd row permutation: key k -> row (k&32)+((k&1)<<4)+((k&31)>>1)
        {
            const int key = tid >> 2, ch = tid & 3;
            const uint4 t4 = *(const uint4*)(Kbase + (size_t)(kb + key) * 32 + ch * 8);
            const int row = (key & 32) + ((key & 1) << 4) + ((key & 31) >> 1);
            *(uint4*)(&Ks[row * KS_STRIDE + ch * 8]) = t4;
        }
        // V tile: 24 d-rows x 64 keys, natural order
        if (tid < 192) {
            const int d = tid >> 3, ch = tid & 7;
            const uint4 t4 = *(const uint4*)(Vbase + (size_t)d * 4096 + kb + ch * 8);
            *(uint4*)(&Vs[d * VS_STRIDE + ch * 8]) = t4;
        }
        __syncthreads();

        #pragma unroll
        for (int g = 0; g < 2; ++g) {
            const bfrag Kf0 = *(const bfrag*)(&Ks[(g * 32 + col) * KS_STRIDE + quad * 8]);
            const bfrag Kf1 = *(const bfrag*)(&Ks[(g * 32 + 16 + col) * KS_STRIDE + quad * 8]);
            ffrag S0 = {0.f, 0.f, 0.f, 0.f};
            ffrag S1 = {0.f, 0.f, 0.f, 0.f};
            S0 = __builtin_amdgcn_mfma_f32_16x16x32_bf16(Qf, Kf0, S0, 0, 0, 0); // even keys
            S1 = __builtin_amdgcn_mfma_f32_16x16x32_bf16(Qf, Kf1, S1, 0, 0, 0); // odd keys
            #pragma unroll
            for (int r = 0; r < 4; ++r) {
                const float p0 = exp2f(S0[r]);   // key 2*col
                const float p1 = exp2f(S1[r]);   // key 2*col+1
                lacc[r] += p0 + p1;
                *(unsigned int*)(&Pw[(quad * 4 + r) * PS_STRIDE + col * 2]) = pack2(p0, p1);
            }
            const bfrag Pf  = *(const bfrag*)(&Pw[col * PS_STRIDE + quad * 8]);
            const bfrag Vf0 = *(const bfrag*)(&Vs[col * VS_STRIDE + g * 32 + quad * 8]);
            const bfrag Vf1 = *(const bfrag*)(&Vs[(16 + col) * VS_STRIDE + g * 32 + quad * 8]);
            O0 = __builtin_amdgcn_mfma_f32_16x16x32_bf16(Pf, Vf0, O0, 0, 0, 0);
            O1 = __builtin_amdgcn_mfma_f32_16x16x32_bf16(Pf, Vf1, O1, 0, 0, 0);
        }
        __syncthreads();
    }

    // reduce l over the 16 key-lanes; store partials
    #pragma unroll
    for (int r = 0; r < 4; ++r) {
        float v = lacc[r];
        v += __shfl_xor(v, 1);
        v += __shfl_xor(v, 2);
        v += __shfl_xor(v, 4);
        v += __shfl_xor(v, 8);
        if (col == 0)
            lpart[(size_t)split * N_ + qbase + quad * 4 + r] = v;
    }
    #pragma unroll
    for (int r = 0; r < 4; ++r) {
        const size_t base = ((size_t)split * N_ + qbase + quad * 4 + r) * 32;
        Opart[base + col]      = O0[r];
        Opart[base + 16 + col] = O1[r];  // cols 8..15 are junk d>=24, masked in combine
    }
}

// ---------------- Kernel 3: combine + output projection ----------------
// 64 queries/block. Sum split partials, H = O/l -> bf16 LDS, wO MFMA, store.
__global__ __launch_bounds__(256) void combine_kernel(
    const float* __restrict__ Opart, const float* __restrict__ lpart,
    const unsigned short* __restrict__ wOf, const float* __restrict__ bO,
    float* __restrict__ out, int nsp)
{
    __shared__ unsigned short Hs[64 * HS_STRIDE];

    const int tid = threadIdx.x;
    const int qb  = blockIdx.x * 64;
    {
        const int ql = tid >> 2;
        const int c8 = (tid & 3) * 8;     // dim chunk 0,8,16,24
        const int q  = qb + ql;
        float a[8] = {0.f, 0.f, 0.f, 0.f, 0.f, 0.f, 0.f, 0.f};
        if (c8 < 24) {                    // chunk 24..31 is junk -> zeros
            for (int s = 0; s < nsp; ++s) {
                const float* p = &Opart[((size_t)s * N_ + q) * 32 + c8];
                const float4 u = *(const float4*)p;
                const float4 v = *(const float4*)(p + 4);
                a[0] += u.x; a[1] += u.y; a[2] += u.z; a[3] += u.w;
                a[4] += v.x; a[5] += v.y; a[6] += v.z; a[7] += v.w;
            }
        }
        float ls = 0.f;
        for (int s = 0; s < nsp; ++s) ls += lpart[(size_t)s * N_ + q];
        const float inv = 1.0f / ls;
        uint4 pk;
        pk.x = pack2(a[0] * inv, a[1] * inv);
        pk.y = pack2(a[2] * inv, a[3] * inv);
        pk.z = pack2(a[4] * inv, a[5] * inv);
        pk.w = pack2(a[6] * inv, a[7] * inv);
        *(uint4*)(&Hs[ql * HS_STRIDE + c8]) = pk;
    }
    __syncthreads();

    const int lane = tid & 63;
    const int w    = tid >> 6;
    const int col  = lane & 15;
    const int quad = lane >> 4;
    const bfrag Hf = *(const bfrag*)(&Hs[(w * 16 + col) * HS_STRIDE + quad * 8]);
    #pragma unroll
    for (int nt = 0; nt < 8; ++nt) {
        const bfrag Wo = *(const bfrag*)(wOf + (nt * 64 + lane) * 8);
        ffrag C = {0.f, 0.f, 0.f, 0.f};
        C = __builtin_amdgcn_mfma_f32_16x16x32_bf16(Hf, Wo, C, 0, 0, 0);
        const float bo = bO[nt * 16 + col];
        #pragma unroll
        for (int r = 0; r < 4; ++r)
            out[(size_t)(qb + w * 16 + quad * 4 + r) * 128 + nt * 16 + col] = C[r] + bo;
    }
}

extern "C" void kernel_launch(void* const* d_in, const int* in_sizes, int n_in,
                              void* d_out, int out_size, void* d_ws, size_t ws_size,
                              hipStream_t stream) {
    const float* x  = (const float*)d_in[0];
    const float* wQ = (const float*)d_in[1];
    const float* bQ = (const float*)d_in[2];
    const float* wK = (const float*)d_in[3];
    const float* bK = (const float*)d_in[4];
    const float* wV = (const float*)d_in[5];
    const float* bV = (const float*)d_in[6];
    const float* wO = (const float*)d_in[7];
    const float* bO = (const float*)d_in[8];
    float* out = (float*)d_out;

    unsigned short* ws16 = (unsigned short*)d_ws;
    unsigned short* Qbf = ws16;                                    // N*32 shorts
    unsigned short* Kbf = Qbf + (size_t)N_ * 32;                   // N*32
    unsigned short* Vt  = Kbf + (size_t)N_ * 32;                   // B*24*S
    unsigned short* Wf  = Vt + (size_t)B_ * 24 * S_;               // 10240
    unsigned short* wOf = Wf + 4 * 5 * 512;                        // 4096
    float* bqkv = (float*)(wOf + 8 * 512);                         // 80 fp32
    float* Opart = bqkv + 80;                                      // nsp*N*32 fp32
    const size_t baseBytes = (size_t)((char*)Opart - (char*)d_ws);

    int nsp = 4;
    while (nsp > 1) {
        const size_t need = baseBytes + (size_t)nsp * N_ * 32 * 4 + (size_t)nsp * N_ * 4;
        if (need <= ws_size) break;
        nsp >>= 1;
    }
    float* lpart = Opart + (size_t)nsp * N_ * 32;

    prep_kernel<<<1, 256, 0, stream>>>(wQ, bQ, wK, bK, wV, bV, wO, Wf, wOf, bqkv);
    proj_kernel<<<N_ / 64, 256, 0, stream>>>(x, Wf, bqkv, Qbf, Kbf, Vt);
    attn_kernel<<<dim3(N_ / 64, nsp), 256, 0, stream>>>(Qbf, Kbf, Vt, Opart, lpart);
    combine_kernel<<<N_ / 64, 256, 0, stream>>>(Opart, lpart, wOf, bO, out, nsp);
}

// Round 6
// 136.010 us; speedup vs baseline: 9.1814x; 1.2176x over previous
//
#include <hip/hip_runtime.h>

// MyEncoder: B=8, S=4096, E=128, D=24, fp32 in/out.
// out = softmax((xWq+bq)(xWk+bk)^T / sqrt(128)) (xWv+bv) Wo + bo
// bf16-MFMA pipeline: prep -> proj (QKV GEMM) -> attn (flash partials,
// K-split, transposed-score in-register-P) -> combine (sum + wO epilogue).
// Softmax without max-subtraction (scores tiny, shift-invariant) => K-split
// partials purely additive. exp2 with log2(e) folded into Q scale.
//
// attn math (per 16-key chunk):
//   S^T = mfma(A=K_frag, B=Q_frag)        -> lane holds S^T[key=quad*4+r][q=col]
//   P = exp2(S^T)                          (stays in registers)
//   O^T += mfma(A=V^T zero-gapped, B=P)    B[k=quad*8+j] = P_r (j=r<4), 0 (j>=4)
// C-layout of O^T: lane(col,quad) holds O^T[d=quad*4+reg][q=col] (+16 for Ot1).

#define B_ 8
#define S_ 4096
#define E_ 128
#define D_ 24
#define N_ (B_ * S_)               // 32768 rows
#define SCALE 0.08838834764831845f // 1/sqrt(128)
#define LOG2E 1.4426950408889634f

#define TK 64                      // keys per LDS tile in attn
#define KS_STRIDE 40               // K_s row stride (shorts)
#define VS_STRIDE 136              // V_s row stride (shorts): 4 chunks*32 + 8 pad
#define HS_STRIDE 40               // H_s row stride in combine
#define XS_STRIDE 136              // x_s row stride (bf16) in proj
#define OS_STRIDE 84               // out_s row stride (fp32) in proj

typedef __attribute__((ext_vector_type(8))) short bfrag;   // 8 bf16 = 4 VGPR
typedef __attribute__((ext_vector_type(4))) float ffrag;   // 4 fp32 acc

__device__ inline unsigned short f2bf(float f) {           // RNE fp32->bf16
    unsigned int x = __builtin_bit_cast(unsigned int, f);
    return (unsigned short)((x + 0x7fffu + ((x >> 16) & 1u)) >> 16);
}
__device__ inline unsigned int pack2(float a, float b) {
    return (unsigned int)f2bf(a) | ((unsigned int)f2bf(b) << 16);
}
// round-half-up bf16 pair pack: 2 int-adds + v_perm (cheap, <=1ulp vs RNE on ties)
__device__ inline unsigned int pack2h(float a, float b) {
    unsigned int ua = __builtin_bit_cast(unsigned int, a) + 0x8000u;
    unsigned int ub = __builtin_bit_cast(unsigned int, b) + 0x8000u;
    return __builtin_amdgcn_perm(ub, ua, 0x07060302);      // [ua.hi16 | ub.hi16]
}

// ---------------- Kernel 0: weight prep (8 blocks) ----------------
// Wf  [kt=4][nt=5][lane=64][j=8]: W[k][n], k=kt*32+quad*8+j, n=nt*16+(lane&15)
//     W = [wQ*SCALE*LOG2E | wK | wV | 0pad] (128 x 80)
// wOf [nt=8][lane=64][j=8]: wO[k][e], k=quad*8+j (zero for k>=24)
// bqkv[80] fp32 = [bQ*SCALE*LOG2E | bK | bV | 0]
__global__ __launch_bounds__(256) void prep_kernel(
    const float* __restrict__ wQ, const float* __restrict__ bQ,
    const float* __restrict__ wK, const float* __restrict__ bK,
    const float* __restrict__ wV, const float* __restrict__ bV,
    const float* __restrict__ wO,
    unsigned short* __restrict__ Wf, unsigned short* __restrict__ wOf,
    float* __restrict__ bqkv)
{
    const int gtid   = blockIdx.x * 256 + threadIdx.x;
    const int stride = gridDim.x * 256;
    const float qs = SCALE * LOG2E;
    for (int idx = gtid; idx < 4 * 5 * 512; idx += stride) {
        const int j    = idx & 7;
        const int lane = (idx >> 3) & 63;
        const int nt   = (idx >> 9) % 5;
        const int kt   = idx / 2560;
        const int n = nt * 16 + (lane & 15);
        const int k = kt * 32 + ((lane >> 4) << 3) + j;
        float v = 0.0f;
        if (n < 24)      v = wQ[k * 24 + n] * qs;
        else if (n < 48) v = wK[k * 24 + (n - 24)];
        else if (n < 72) v = wV[k * 24 + (n - 48)];
        Wf[idx] = f2bf(v);
    }
    for (int idx = gtid; idx < 8 * 512; idx += stride) {
        const int j    = idx & 7;
        const int lane = (idx >> 3) & 63;
        const int nt   = idx >> 9;
        const int k = ((lane >> 4) << 3) + j;
        const int e = nt * 16 + (lane & 15);
        wOf[idx] = (k < 24) ? f2bf(wO[k * 128 + e]) : (unsigned short)0;
    }
    if (gtid < 80) {
        float v = 0.0f;
        if (gtid < 24)      v = bQ[gtid] * qs;
        else if (gtid < 48) v = bK[gtid - 24];
        else if (gtid < 72) v = bV[gtid - 48];
        bqkv[gtid] = v;
    }
}

// ---------------- Kernel 1: QKV projection (MFMA) ----------------
// 64 rows/block, 4 waves x 16 rows. x (fp32) -> bf16 LDS; W frags from Wf.
// Epilogue: bias add -> LDS fp32 tile -> Qbf/Kbf (row-major, 32-padded) and
// Vt (transposed, [b][d][s]).
__global__ __launch_bounds__(256) void proj_kernel(
    const float* __restrict__ x, const unsigned short* __restrict__ Wf,
    const float* __restrict__ bqkv,
    unsigned short* __restrict__ Qbf, unsigned short* __restrict__ Kbf,
    unsigned short* __restrict__ Vt)
{
    __shared__ float smem[64 * OS_STRIDE];          // 21504 B, dual-purpose
    unsigned short* xs = (unsigned short*)smem;     // [64][XS_STRIDE]
    float* os = smem;                               // [64][OS_STRIDE]

    const int tid  = threadIdx.x;
    const int lane = tid & 63;
    const int w    = tid >> 6;
    const int col  = lane & 15;
    const int quad = lane >> 4;
    const int rb   = blockIdx.x * 64;

    #pragma unroll
    for (int i = 0; i < 8; ++i) {
        const int idx = i * 256 + tid;
        const int row = idx >> 5, c4 = idx & 31;
        const float4 xv = *(const float4*)(x + (size_t)(rb + row) * 128 + c4 * 4);
        uint2 h;
        h.x = pack2(xv.x, xv.y);
        h.y = pack2(xv.z, xv.w);
        *(uint2*)(&xs[row * XS_STRIDE + c4 * 4]) = h;
    }

    bfrag Wfr[20];
    #pragma unroll
    for (int f = 0; f < 20; ++f)
        Wfr[f] = *(const bfrag*)(Wf + (f * 64 + lane) * 8);

    __syncthreads();

    ffrag acc[5];
    #pragma unroll
    for (int nt = 0; nt < 5; ++nt) acc[nt] = (ffrag){0.f, 0.f, 0.f, 0.f};

    #pragma unroll
    for (int kt = 0; kt < 4; ++kt) {
        const bfrag Af = *(const bfrag*)(&xs[(w * 16 + col) * XS_STRIDE + kt * 32 + quad * 8]);
        #pragma unroll
        for (int nt = 0; nt < 5; ++nt)
            acc[nt] = __builtin_amdgcn_mfma_f32_16x16x32_bf16(Af, Wfr[kt * 5 + nt], acc[nt], 0, 0, 0);
    }

    __syncthreads();

    #pragma unroll
    for (int nt = 0; nt < 5; ++nt) {
        const float bb = bqkv[nt * 16 + col];
        #pragma unroll
        for (int r = 0; r < 4; ++r)
            os[(w * 16 + quad * 4 + r) * OS_STRIDE + nt * 16 + col] = acc[nt][r] + bb;
    }
    __syncthreads();

    // Q (tid<128) / K (tid>=128): row-major bf16, cols padded to 32
    {
        const int half  = tid & 1;
        const int row   = (tid >> 1) & 63;
        const int isK   = tid >> 7;
        const int cbase = isK * 24;
        unsigned int pk[8];
        #pragma unroll
        for (int g = 0; g < 8; ++g) {
            const int c0 = half * 16 + g * 2;
            const float f0 = (c0     < 24) ? os[row * OS_STRIDE + cbase + c0]     : 0.0f;
            const float f1 = (c0 + 1 < 24) ? os[row * OS_STRIDE + cbase + c0 + 1] : 0.0f;
            pk[g] = pack2(f0, f1);
        }
        unsigned short* dst = (isK ? Kbf : Qbf) + (size_t)(rb + row) * 32 + half * 16;
        *(uint4*)(dst)     = make_uint4(pk[0], pk[1], pk[2], pk[3]);
        *(uint4*)(dst + 8) = make_uint4(pk[4], pk[5], pk[6], pk[7]);
    }

    // Vt: transposed [b][d][s], 16B stores
    if (tid < 192) {
        const int d  = tid % 24;
        const int ch = tid / 24;
        unsigned int p[4];
        #pragma unroll
        for (int g = 0; g < 4; ++g) {
            const float f0 = os[(ch * 8 + g * 2 + 0) * OS_STRIDE + 48 + d];
            const float f1 = os[(ch * 8 + g * 2 + 1) * OS_STRIDE + 48 + d];
            p[g] = pack2(f0, f1);
        }
        const int b = rb >> 12, s0 = rb & 4095;
        uint4* dst = (uint4*)(Vt + (((size_t)(b * 24 + d)) << 12) + s0 + ch * 8);
        *dst = make_uint4(p[0], p[1], p[2], p[3]);
    }
}

// ---------------- Kernel 2: flash attention partials (transposed scores) ---
// Grid (N/64, KSP). 64 queries/block (4 waves x 16). P never touches LDS.
// V staged zero-gapped: Vs[d][c*32 + quad*8 + j] = V[c*16+quad*4+j][d], j<4;
// slots j>=4 zeroed once (MFMA B has zeros there; A must be finite: 0*NaN=NaN).
__global__ __launch_bounds__(256, 8) void attn_kernel(
    const unsigned short* __restrict__ Qbf, const unsigned short* __restrict__ Kbf,
    const unsigned short* __restrict__ Vt,
    float* __restrict__ Opart, float* __restrict__ lpart)
{
    __shared__ unsigned short Ks[TK * KS_STRIDE];     // 5120 B
    __shared__ unsigned short Vs[32 * VS_STRIDE];     // 8704 B

    const int tid    = threadIdx.x;
    const int lane   = tid & 63;
    const int w      = tid >> 6;
    const int col    = lane & 15;
    const int quad   = lane >> 4;
    const int blk    = blockIdx.x;
    const int split  = blockIdx.y;
    const int nsp    = gridDim.y;
    const int kchunk = S_ / nsp;
    const int b      = blk >> 6;
    const int qbase  = blk * 64 + w * 16;

    // zero-init Vs (incl. gap slots and rows 24-31) once
    #pragma unroll
    for (int i0 = 0; i0 < 3; ++i0) {
        const int i = i0 * 256 + tid;
        if (i < 32 * VS_STRIDE / 8)
            *(uint4*)(&Vs[i * 8]) = make_uint4(0u, 0u, 0u, 0u);
    }

    const bfrag Qf = *(const bfrag*)(Qbf + (size_t)(qbase + col) * 32 + quad * 8);

    ffrag Ot0 = {0.f, 0.f, 0.f, 0.f};   // O^T d = quad*4+reg      (0..15)
    ffrag Ot1 = {0.f, 0.f, 0.f, 0.f};   // O^T d = 16+quad*4+reg   (16..31; >=24 junk)
    float lacc = 0.0f;

    const unsigned short* Kbase = Kbf + ((size_t)(b * 4096) + split * kchunk) * 32;
    const unsigned short* Vbase = Vt + (size_t)(b * 24) * 4096 + split * kchunk;

    __syncthreads();   // Vs zero-init complete

    for (int kb = 0; kb < kchunk; kb += TK) {
        // K tile: natural order, 64 rows x 32 bf16
        {
            const int key = tid >> 2, ch = tid & 3;
            const uint4 t4 = *(const uint4*)(Kbase + (size_t)(kb + key) * 32 + ch * 8);
            *(uint4*)(&Ks[key * KS_STRIDE + ch * 8]) = t4;
        }
        // V tile: 24 d-rows x 64 keys, zero-gapped 4-key groups (b64 units)
        #pragma unroll
        for (int u0 = 0; u0 < 2; ++u0) {
            const int u = u0 * 256 + tid;
            if (u < 384) {
                const int d = u >> 4, cq = u & 15, c = cq >> 2, qd = cq & 3;
                const uint2 t2 = *(const uint2*)(Vbase + (size_t)d * 4096 + kb + c * 16 + qd * 4);
                *(uint2*)(&Vs[d * VS_STRIDE + c * 32 + qd * 8]) = t2;
            }
        }
        __syncthreads();

        #pragma unroll
        for (int c = 0; c < 4; ++c) {
            // S^T = K . Q^T  (operand swap; same fragment layouts)
            const bfrag Kf = *(const bfrag*)(&Ks[(c * 16 + col) * KS_STRIDE + quad * 8]);
            ffrag S = {0.f, 0.f, 0.f, 0.f};
            S = __builtin_amdgcn_mfma_f32_16x16x32_bf16(Kf, Qf, S, 0, 0, 0);
            const float p0 = __builtin_amdgcn_exp2f(S[0]);
            const float p1 = __builtin_amdgcn_exp2f(S[1]);
            const float p2 = __builtin_amdgcn_exp2f(S[2]);
            const float p3 = __builtin_amdgcn_exp2f(S[3]);
            lacc += (p0 + p1) + (p2 + p3);
            union { bfrag f; unsigned int u[4]; } P;
            P.u[0] = pack2h(p0, p1);
            P.u[1] = pack2h(p2, p3);
            P.u[2] = 0u; P.u[3] = 0u;
            // O^T += V^T . P^T   (A rows = d, K-dim = 16 real keys + 16 zeros)
            const bfrag Va0 = *(const bfrag*)(&Vs[col * VS_STRIDE + c * 32 + quad * 8]);
            const bfrag Va1 = *(const bfrag*)(&Vs[(16 + col) * VS_STRIDE + c * 32 + quad * 8]);
            Ot0 = __builtin_amdgcn_mfma_f32_16x16x32_bf16(Va0, P.f, Ot0, 0, 0, 0);
            Ot1 = __builtin_amdgcn_mfma_f32_16x16x32_bf16(Va1, P.f, Ot1, 0, 0, 0);
        }
        __syncthreads();
    }

    // l[q=col] = sum over quads of lacc
    float v = lacc;
    v += __shfl_xor(v, 16);
    v += __shfl_xor(v, 32);
    if (quad == 0)
        lpart[(size_t)split * N_ + qbase + col] = v;

    // O^T partials -> Opart[q][d] (contiguous float4 per lane)
    const size_t base = ((size_t)split * N_ + qbase + col) * 32;
    *(ffrag*)(&Opart[base + quad * 4]) = Ot0;
    if (quad < 2)
        *(ffrag*)(&Opart[base + 16 + quad * 4]) = Ot1;   // d 16..23
}

// ---------------- Kernel 3: combine + output projection ----------------
// 64 queries/block. Sum split partials, H = O/l -> bf16 LDS, wO MFMA, store.
__global__ __launch_bounds__(256) void combine_kernel(
    const float* __restrict__ Opart, const float* __restrict__ lpart,
    const unsigned short* __restrict__ wOf, const float* __restrict__ bO,
    float* __restrict__ out, int nsp)
{
    __shared__ unsigned short Hs[64 * HS_STRIDE];

    const int tid = threadIdx.x;
    const int qb  = blockIdx.x * 64;
    {
        const int ql = tid >> 2;
        const int c8 = (tid & 3) * 8;     // dim chunk 0,8,16,24
        const int q  = qb + ql;
        float a[8] = {0.f, 0.f, 0.f, 0.f, 0.f, 0.f, 0.f, 0.f};
        if (c8 < 24) {                    // chunk 24..31 never written -> zeros
            for (int s = 0; s < nsp; ++s) {
                const float* p = &Opart[((size_t)s * N_ + q) * 32 + c8];
                const float4 u = *(const float4*)p;
                const float4 v = *(const float4*)(p + 4);
                a[0] += u.x; a[1] += u.y; a[2] += u.z; a[3] += u.w;
                a[4] += v.x; a[5] += v.y; a[6] += v.z; a[7] += v.w;
            }
        }
        float ls = 0.f;
        for (int s = 0; s < nsp; ++s) ls += lpart[(size_t)s * N_ + q];
        const float inv = 1.0f / ls;
        uint4 pk;
        pk.x = pack2(a[0] * inv, a[1] * inv);
        pk.y = pack2(a[2] * inv, a[3] * inv);
        pk.z = pack2(a[4] * inv, a[5] * inv);
        pk.w = pack2(a[6] * inv, a[7] * inv);
        *(uint4*)(&Hs[ql * HS_STRIDE + c8]) = pk;
    }
    __syncthreads();

    const int lane = tid & 63;
    const int w    = tid >> 6;
    const int col  = lane & 15;
    const int quad = lane >> 4;
    const bfrag Hf = *(const bfrag*)(&Hs[(w * 16 + col) * HS_STRIDE + quad * 8]);
    #pragma unroll
    for (int nt = 0; nt < 8; ++nt) {
        const bfrag Wo = *(const bfrag*)(wOf + (nt * 64 + lane) * 8);
        ffrag C = {0.f, 0.f, 0.f, 0.f};
        C = __builtin_amdgcn_mfma_f32_16x16x32_bf16(Hf, Wo, C, 0, 0, 0);
        const float bo = bO[nt * 16 + col];
        #pragma unroll
        for (int r = 0; r < 4; ++r)
            out[(size_t)(qb + w * 16 + quad * 4 + r) * 128 + nt * 16 + col] = C[r] + bo;
    }
}

extern "C" void kernel_launch(void* const* d_in, const int* in_sizes, int n_in,
                              void* d_out, int out_size, void* d_ws, size_t ws_size,
                              hipStream_t stream) {
    const float* x  = (const float*)d_in[0];
    const float* wQ = (const float*)d_in[1];
    const float* bQ = (const float*)d_in[2];
    const float* wK = (const float*)d_in[3];
    const float* bK = (const float*)d_in[4];
    const float* wV = (const float*)d_in[5];
    const float* bV = (const float*)d_in[6];
    const float* wO = (const float*)d_in[7];
    const float* bO = (const float*)d_in[8];
    float* out = (float*)d_out;

    unsigned short* ws16 = (unsigned short*)d_ws;
    unsigned short* Qbf = ws16;                                    // N*32 shorts
    unsigned short* Kbf = Qbf + (size_t)N_ * 32;                   // N*32
    unsigned short* Vt  = Kbf + (size_t)N_ * 32;                   // B*24*S
    unsigned short* Wf  = Vt + (size_t)B_ * 24 * S_;               // 10240
    unsigned short* wOf = Wf + 4 * 5 * 512;                        // 4096
    float* bqkv = (float*)(wOf + 8 * 512);                         // 80 fp32
    float* Opart = bqkv + 80;                                      // nsp*N*32 fp32
    const size_t baseBytes = (size_t)((char*)Opart - (char*)d_ws);

    int nsp = 4;
    while (nsp > 1) {
        const size_t need = baseBytes + (size_t)nsp * N_ * 32 * 4 + (size_t)nsp * N_ * 4;
        if (need <= ws_size) break;
        nsp >>= 1;
    }
    float* lpart = Opart + (size_t)nsp * N_ * 32;

    prep_kernel<<<8, 256, 0, stream>>>(wQ, bQ, wK, bK, wV, bV, wO, Wf, wOf, bqkv);
    proj_kernel<<<N_ / 64, 256, 0, stream>>>(x, Wf, bqkv, Qbf, Kbf, Vt);
    attn_kernel<<<dim3(N_ / 64, nsp), 256, 0, stream>>>(Qbf, Kbf, Vt, Opart, lpart);
    combine_kernel<<<N_ / 64, 256, 0, stream>>>(Opart, lpart, wOf, bO, out, nsp);
}

// Round 7
// 125.133 us; speedup vs baseline: 9.9794x; 1.0869x over previous
//
#include <hip/hip_runtime.h>

// MyEncoder: B=8, S=4096, E=128, D=24, fp32 in/out.
// out = softmax((xWq+bq)(xWk+bk)^T / sqrt(128)) (xWv+bv) Wo + bo
// bf16-MFMA pipeline: prep -> proj (QKV GEMM) -> attn (flash partials,
// K-split, transposed scores, in-register P, full-K PV, MFMA-computed l)
// -> combine (sum partials + wO epilogue).
// Softmax without max-subtraction (scores tiny, shift-invariant) => K-split
// partials purely additive. exp2 with log2(e) folded into Q scale.
//
// attn math (per 32-key group c2, keys permuted at staging):
//   chunk e=2*c2:   S^T[key=c2*32+quad*8+r][q=col]   = mfma(A=K_e, B=Q)
//   chunk o=2*c2+1: S^T[key=c2*32+quad*8+4+r][q=col] = mfma(A=K_o, B=Q)
//   P (exp2 of both) packs into ONE full B-frag (k=quad*8+j, j=0..7 real)
//   O^T += mfma(A=V^T natural, B=P)   ; V row d=24 staged as 1.0 => Ot1's
//   d=24 element is l (sum of P) -- no VALU l accumulation needed.

#define B_ 8
#define S_ 4096
#define E_ 128
#define D_ 24
#define N_ (B_ * S_)               // 32768 rows
#define SCALE 0.08838834764831845f // 1/sqrt(128)
#define LOG2E 1.4426950408889634f

#define TK 128                     // keys per LDS tile in attn
#define KS_STRIDE 40               // K_s row stride (shorts)
#define VS_STRIDE 136              // V_s row stride (shorts): 128 + 8 pad
#define HS_STRIDE 40               // H_s row stride in combine
#define XS_STRIDE 136              // x_s row stride (bf16) in proj
#define OS_STRIDE 84               // out_s row stride (fp32) in proj

typedef __attribute__((ext_vector_type(8))) short bfrag;   // 8 bf16 = 4 VGPR
typedef __attribute__((ext_vector_type(4))) float ffrag;   // 4 fp32 acc

__device__ inline unsigned short f2bf(float f) {           // RNE fp32->bf16
    unsigned int x = __builtin_bit_cast(unsigned int, f);
    return (unsigned short)((x + 0x7fffu + ((x >> 16) & 1u)) >> 16);
}
__device__ inline unsigned int pack2(float a, float b) {
    return (unsigned int)f2bf(a) | ((unsigned int)f2bf(b) << 16);
}
// round-half-up bf16 pair pack: 2 int-adds + v_perm (validated r5 on HW)
__device__ inline unsigned int pack2h(float a, float b) {
    unsigned int ua = __builtin_bit_cast(unsigned int, a) + 0x8000u;
    unsigned int ub = __builtin_bit_cast(unsigned int, b) + 0x8000u;
    return __builtin_amdgcn_perm(ub, ua, 0x07060302);      // [a.hi16 | b.hi16]
}

// ---------------- Kernel 0: weight prep (8 blocks) ----------------
__global__ __launch_bounds__(256) void prep_kernel(
    const float* __restrict__ wQ, const float* __restrict__ bQ,
    const float* __restrict__ wK, const float* __restrict__ bK,
    const float* __restrict__ wV, const float* __restrict__ bV,
    const float* __restrict__ wO,
    unsigned short* __restrict__ Wf, unsigned short* __restrict__ wOf,
    float* __restrict__ bqkv)
{
    const int gtid   = blockIdx.x * 256 + threadIdx.x;
    const int stride = gridDim.x * 256;
    const float qs = SCALE * LOG2E;
    for (int idx = gtid; idx < 4 * 5 * 512; idx += stride) {
        const int j    = idx & 7;
        const int lane = (idx >> 3) & 63;
        const int nt   = (idx >> 9) % 5;
        const int kt   = idx / 2560;
        const int n = nt * 16 + (lane & 15);
        const int k = kt * 32 + ((lane >> 4) << 3) + j;
        float v = 0.0f;
        if (n < 24)      v = wQ[k * 24 + n] * qs;
        else if (n < 48) v = wK[k * 24 + (n - 24)];
        else if (n < 72) v = wV[k * 24 + (n - 48)];
        Wf[idx] = f2bf(v);
    }
    for (int idx = gtid; idx < 8 * 512; idx += stride) {
        const int j    = idx & 7;
        const int lane = (idx >> 3) & 63;
        const int nt   = idx >> 9;
        const int k = ((lane >> 4) << 3) + j;
        const int e = nt * 16 + (lane & 15);
        wOf[idx] = (k < 24) ? f2bf(wO[k * 128 + e]) : (unsigned short)0;
    }
    if (gtid < 80) {
        float v = 0.0f;
        if (gtid < 24)      v = bQ[gtid] * qs;
        else if (gtid < 48) v = bK[gtid - 24];
        else if (gtid < 72) v = bV[gtid - 48];
        bqkv[gtid] = v;
    }
}

// ---------------- Kernel 1: QKV projection (MFMA) ----------------
__global__ __launch_bounds__(256) void proj_kernel(
    const float* __restrict__ x, const unsigned short* __restrict__ Wf,
    const float* __restrict__ bqkv,
    unsigned short* __restrict__ Qbf, unsigned short* __restrict__ Kbf,
    unsigned short* __restrict__ Vt)
{
    __shared__ float smem[64 * OS_STRIDE];          // 21504 B, dual-purpose
    unsigned short* xs = (unsigned short*)smem;     // [64][XS_STRIDE]
    float* os = smem;                               // [64][OS_STRIDE]

    const int tid  = threadIdx.x;
    const int lane = tid & 63;
    const int w    = tid >> 6;
    const int col  = lane & 15;
    const int quad = lane >> 4;
    const int rb   = blockIdx.x * 64;

    #pragma unroll
    for (int i = 0; i < 8; ++i) {
        const int idx = i * 256 + tid;
        const int row = idx >> 5, c4 = idx & 31;
        const float4 xv = *(const float4*)(x + (size_t)(rb + row) * 128 + c4 * 4);
        uint2 h;
        h.x = pack2(xv.x, xv.y);
        h.y = pack2(xv.z, xv.w);
        *(uint2*)(&xs[row * XS_STRIDE + c4 * 4]) = h;
    }

    bfrag Wfr[20];
    #pragma unroll
    for (int f = 0; f < 20; ++f)
        Wfr[f] = *(const bfrag*)(Wf + (f * 64 + lane) * 8);

    __syncthreads();

    ffrag acc[5];
    #pragma unroll
    for (int nt = 0; nt < 5; ++nt) acc[nt] = (ffrag){0.f, 0.f, 0.f, 0.f};

    #pragma unroll
    for (int kt = 0; kt < 4; ++kt) {
        const bfrag Af = *(const bfrag*)(&xs[(w * 16 + col) * XS_STRIDE + kt * 32 + quad * 8]);
        #pragma unroll
        for (int nt = 0; nt < 5; ++nt)
            acc[nt] = __builtin_amdgcn_mfma_f32_16x16x32_bf16(Af, Wfr[kt * 5 + nt], acc[nt], 0, 0, 0);
    }

    __syncthreads();

    #pragma unroll
    for (int nt = 0; nt < 5; ++nt) {
        const float bb = bqkv[nt * 16 + col];
        #pragma unroll
        for (int r = 0; r < 4; ++r)
            os[(w * 16 + quad * 4 + r) * OS_STRIDE + nt * 16 + col] = acc[nt][r] + bb;
    }
    __syncthreads();

    // Q (tid<128) / K (tid>=128): row-major bf16, cols padded to 32
    {
        const int half  = tid & 1;
        const int row   = (tid >> 1) & 63;
        const int isK   = tid >> 7;
        const int cbase = isK * 24;
        unsigned int pk[8];
        #pragma unroll
        for (int g = 0; g < 8; ++g) {
            const int c0 = half * 16 + g * 2;
            const float f0 = (c0     < 24) ? os[row * OS_STRIDE + cbase + c0]     : 0.0f;
            const float f1 = (c0 + 1 < 24) ? os[row * OS_STRIDE + cbase + c0 + 1] : 0.0f;
            pk[g] = pack2(f0, f1);
        }
        unsigned short* dst = (isK ? Kbf : Qbf) + (size_t)(rb + row) * 32 + half * 16;
        *(uint4*)(dst)     = make_uint4(pk[0], pk[1], pk[2], pk[3]);
        *(uint4*)(dst + 8) = make_uint4(pk[4], pk[5], pk[6], pk[7]);
    }

    // Vt: transposed [b][d][s], 16B stores
    if (tid < 192) {
        const int d  = tid % 24;
        const int ch = tid / 24;
        unsigned int p[4];
        #pragma unroll
        for (int g = 0; g < 4; ++g) {
            const float f0 = os[(ch * 8 + g * 2 + 0) * OS_STRIDE + 48 + d];
            const float f1 = os[(ch * 8 + g * 2 + 1) * OS_STRIDE + 48 + d];
            p[g] = pack2(f0, f1);
        }
        const int b = rb >> 12, s0 = rb & 4095;
        uint4* dst = (uint4*)(Vt + (((size_t)(b * 24 + d)) << 12) + s0 + ch * 8);
        *dst = make_uint4(p[0], p[1], p[2], p[3]);
    }
}

// ---------------- Kernel 2: flash attention partials ----------------
// Grid (N/64, KSP). 64 queries/block (4 waves x 16). P in registers only.
// K staged permuted: key k -> Ks row (k&~31) + (((k>>2)&1)<<4) + (((k&31)>>3)<<2) + (k&3)
// so chunk 2*c2 gives keys quad*8+r, chunk 2*c2+1 gives quad*8+4+r -> one
// full K=32 P fragment per 32 keys. V natural order; V row d=24 = 1.0 so
// the PV MFMA computes l in Ot1's d=24 element.
__global__ __launch_bounds__(256, 8) void attn_kernel(
    const unsigned short* __restrict__ Qbf, const unsigned short* __restrict__ Kbf,
    const unsigned short* __restrict__ Vt,
    float* __restrict__ Opart, float* __restrict__ lpart)
{
    __shared__ unsigned short Ks[TK * KS_STRIDE];     // 10240 B
    __shared__ unsigned short Vs[32 * VS_STRIDE];     // 8704 B (rows 25-31 unused)

    const int tid    = threadIdx.x;
    const int lane   = tid & 63;
    const int w      = tid >> 6;
    const int col    = lane & 15;
    const int quad   = lane >> 4;
    const int blk    = blockIdx.x;
    const int split  = blockIdx.y;
    const int nsp    = gridDim.y;
    const int kchunk = S_ / nsp;
    const int b      = blk >> 6;
    const int qbase  = blk * 64 + w * 16;

    // ones row d=24 (written once; staging only touches rows 0..23)
    if (tid < 16)
        *(uint4*)(&Vs[24 * VS_STRIDE + tid * 8]) =
            make_uint4(0x3F803F80u, 0x3F803F80u, 0x3F803F80u, 0x3F803F80u);

    const bfrag Qf = *(const bfrag*)(Qbf + (size_t)(qbase + col) * 32 + quad * 8);

    ffrag Ot0 = {0.f, 0.f, 0.f, 0.f};   // O^T d = quad*4+r        (0..15)
    ffrag Ot1 = {0.f, 0.f, 0.f, 0.f};   // O^T d = 16+quad*4+r     (16..31; d=24 is l)

    const unsigned short* Kbase = Kbf + ((size_t)(b * 4096) + split * kchunk) * 32;
    const unsigned short* Vbase = Vt + (size_t)(b * 24) * 4096 + split * kchunk;

    __syncthreads();   // ones row visible

    for (int kb = 0; kb < kchunk; kb += TK) {
        // K tile: permuted rows, 128 keys x 32 bf16
        #pragma unroll
        for (int i = 0; i < 2; ++i) {
            const int idx = i * 256 + tid;            // 0..511
            const int key = idx >> 2, ch = idx & 3;
            const uint4 t4 = *(const uint4*)(Kbase + (size_t)(kb + key) * 32 + ch * 8);
            const int row = (key & ~31) + (((key >> 2) & 1) << 4)
                          + (((key & 31) >> 3) << 2) + (key & 3);
            *(uint4*)(&Ks[row * KS_STRIDE + ch * 8]) = t4;
        }
        // V tile: 24 d-rows x 128 keys, natural order
        #pragma unroll
        for (int i = 0; i < 2; ++i) {
            const int u = i * 256 + tid;
            if (u < 384) {
                const int d = u >> 4, ch = u & 15;
                const uint4 t4 = *(const uint4*)(Vbase + (size_t)d * 4096 + kb + ch * 8);
                *(uint4*)(&Vs[d * VS_STRIDE + ch * 8]) = t4;
            }
        }
        __syncthreads();

        #pragma unroll
        for (int c2 = 0; c2 < 4; ++c2) {
            const bfrag Kfe = *(const bfrag*)(&Ks[(c2 * 32 + col) * KS_STRIDE + quad * 8]);
            const bfrag Kfo = *(const bfrag*)(&Ks[(c2 * 32 + 16 + col) * KS_STRIDE + quad * 8]);
            ffrag Se = {0.f, 0.f, 0.f, 0.f};
            ffrag So = {0.f, 0.f, 0.f, 0.f};
            Se = __builtin_amdgcn_mfma_f32_16x16x32_bf16(Kfe, Qf, Se, 0, 0, 0);
            So = __builtin_amdgcn_mfma_f32_16x16x32_bf16(Kfo, Qf, So, 0, 0, 0);
            const float pe0 = __builtin_amdgcn_exp2f(Se[0]);
            const float pe1 = __builtin_amdgcn_exp2f(Se[1]);
            const float pe2 = __builtin_amdgcn_exp2f(Se[2]);
            const float pe3 = __builtin_amdgcn_exp2f(Se[3]);
            const float po0 = __builtin_amdgcn_exp2f(So[0]);
            const float po1 = __builtin_amdgcn_exp2f(So[1]);
            const float po2 = __builtin_amdgcn_exp2f(So[2]);
            const float po3 = __builtin_amdgcn_exp2f(So[3]);
            union { bfrag f; unsigned int u[4]; } P;
            P.u[0] = pack2h(pe0, pe1);   // k=quad*8+0,1
            P.u[1] = pack2h(pe2, pe3);   // k=quad*8+2,3
            P.u[2] = pack2h(po0, po1);   // k=quad*8+4,5
            P.u[3] = pack2h(po2, po3);   // k=quad*8+6,7
            const bfrag Va0 = *(const bfrag*)(&Vs[col * VS_STRIDE + c2 * 32 + quad * 8]);
            const bfrag Va1 = *(const bfrag*)(&Vs[(16 + col) * VS_STRIDE + c2 * 32 + quad * 8]);
            Ot0 = __builtin_amdgcn_mfma_f32_16x16x32_bf16(Va0, P.f, Ot0, 0, 0, 0);
            Ot1 = __builtin_amdgcn_mfma_f32_16x16x32_bf16(Va1, P.f, Ot1, 0, 0, 0);
        }
        __syncthreads();
    }

    // store partials: O^T -> Opart[q][d]; l from Ot1 (d=24 row = quad 2, r=0)
    const size_t base = ((size_t)split * N_ + qbase + col) * 32;
    *(ffrag*)(&Opart[base + quad * 4]) = Ot0;
    if (quad < 2)
        *(ffrag*)(&Opart[base + 16 + quad * 4]) = Ot1;   // d 16..23
    if (quad == 2)
        lpart[(size_t)split * N_ + qbase + col] = Ot1[0]; // d=24 = sum(P) = l
}

// ---------------- Kernel 3: combine + output projection ----------------
__global__ __launch_bounds__(256) void combine_kernel(
    const float* __restrict__ Opart, const float* __restrict__ lpart,
    const unsigned short* __restrict__ wOf, const float* __restrict__ bO,
    float* __restrict__ out, int nsp)
{
    __shared__ unsigned short Hs[64 * HS_STRIDE];

    const int tid = threadIdx.x;
    const int qb  = blockIdx.x * 64;
    {
        const int ql = tid >> 2;
        const int c8 = (tid & 3) * 8;     // dim chunk 0,8,16,24
        const int q  = qb + ql;
        float a[8] = {0.f, 0.f, 0.f, 0.f, 0.f, 0.f, 0.f, 0.f};
        if (c8 < 24) {                    // chunk 24..31 never written -> zeros
            for (int s = 0; s < nsp; ++s) {
                const float* p = &Opart[((size_t)s * N_ + q) * 32 + c8];
                const float4 u = *(const float4*)p;
                const float4 v = *(const float4*)(p + 4);
                a[0] += u.x; a[1] += u.y; a[2] += u.z; a[3] += u.w;
                a[4] += v.x; a[5] += v.y; a[6] += v.z; a[7] += v.w;
            }
        }
        float ls = 0.f;
        for (int s = 0; s < nsp; ++s) ls += lpart[(size_t)s * N_ + q];
        const float inv = 1.0f / ls;
        uint4 pk;
        pk.x = pack2(a[0] * inv, a[1] * inv);
        pk.y = pack2(a[2] * inv, a[3] * inv);
        pk.z = pack2(a[4] * inv, a[5] * inv);
        pk.w = pack2(a[6] * inv, a[7] * inv);
        *(uint4*)(&Hs[ql * HS_STRIDE + c8]) = pk;
    }
    __syncthreads();

    const int lane = tid & 63;
    const int w    = tid >> 6;
    const int col  = lane & 15;
    const int quad = lane >> 4;
    const bfrag Hf = *(const bfrag*)(&Hs[(w * 16 + col) * HS_STRIDE + quad * 8]);
    #pragma unroll
    for (int nt = 0; nt < 8; ++nt) {
        const bfrag Wo = *(const bfrag*)(wOf + (nt * 64 + lane) * 8);
        ffrag C = {0.f, 0.f, 0.f, 0.f};
        C = __builtin_amdgcn_mfma_f32_16x16x32_bf16(Hf, Wo, C, 0, 0, 0);
        const float bo = bO[nt * 16 + col];
        #pragma unroll
        for (int r = 0; r < 4; ++r)
            out[(size_t)(qb + w * 16 + quad * 4 + r) * 128 + nt * 16 + col] = C[r] + bo;
    }
}

extern "C" void kernel_launch(void* const* d_in, const int* in_sizes, int n_in,
                              void* d_out, int out_size, void* d_ws, size_t ws_size,
                              hipStream_t stream) {
    const float* x  = (const float*)d_in[0];
    const float* wQ = (const float*)d_in[1];
    const float* bQ = (const float*)d_in[2];
    const float* wK = (const float*)d_in[3];
    const float* bK = (const float*)d_in[4];
    const float* wV = (const float*)d_in[5];
    const float* bV = (const float*)d_in[6];
    const float* wO = (const float*)d_in[7];
    const float* bO = (const float*)d_in[8];
    float* out = (float*)d_out;

    unsigned short* ws16 = (unsigned short*)d_ws;
    unsigned short* Qbf = ws16;                                    // N*32 shorts
    unsigned short* Kbf = Qbf + (size_t)N_ * 32;                   // N*32
    unsigned short* Vt  = Kbf + (size_t)N_ * 32;                   // B*24*S
    unsigned short* Wf  = Vt + (size_t)B_ * 24 * S_;               // 10240
    unsigned short* wOf = Wf + 4 * 5 * 512;                        // 4096
    float* bqkv = (float*)(wOf + 8 * 512);                         // 80 fp32
    float* Opart = bqkv + 80;                                      // nsp*N*32 fp32
    const size_t baseBytes = (size_t)((char*)Opart - (char*)d_ws);

    int nsp = 4;
    while (nsp > 1) {
        const size_t need = baseBytes + (size_t)nsp * N_ * 32 * 4 + (size_t)nsp * N_ * 4;
        if (need <= ws_size) break;
        nsp >>= 1;
    }
    float* lpart = Opart + (size_t)nsp * N_ * 32;

    prep_kernel<<<8, 256, 0, stream>>>(wQ, bQ, wK, bK, wV, bV, wO, Wf, wOf, bqkv);
    proj_kernel<<<N_ / 64, 256, 0, stream>>>(x, Wf, bqkv, Qbf, Kbf, Vt);
    attn_kernel<<<dim3(N_ / 64, nsp), 256, 0, stream>>>(Qbf, Kbf, Vt, Opart, lpart);
    combine_kernel<<<N_ / 64, 256, 0, stream>>>(Opart, lpart, wOf, bO, out, nsp);
}